// Round 1
// baseline (141.274 us; speedup 1.0000x reference)
//
#include <hip/hip_runtime.h>
#include <math.h>

// ---------------------------------------------------------------------------
// HierarchicalCubeMap, round 3: gather-ready "footprint" layout for the hot
// mip levels (>=3). For each level-l texel-cell index (i,j) in an
// (R+1)x(R+1) grid (i = floor(u*R-0.5)+1, so all clamp edge cases are
// precomputed exactly), we store the clamped 2x2 RGB footprint packed as
// 12 floats in a 64B-aligned slot. One bilinear tap = 3 contiguous
// global_load_dwordx4 from ONE cache line (was 4 scattered lines).
// Per ray: 16 scattered lines -> 4 lines, 16 load instrs -> 12.
//
// ws layout (float4 units):
//   pyr1 plain (512 base, levels 1..9): [0 .. 524286)
//   pyr0 plain (128 base, levels 1..7): [524286 .. 557052)
//   footprints (levels >=3, both pyrs): [557052 .. 557052 + 36780*4)
// ---------------------------------------------------------------------------

#define NPYR1_4 524286
#define FPB 557052   // float4 offset of footprint region (64B aligned)
#define NFP 36780    // total footprint slots

// plain-level offsets in float4 units, index = level-1
__device__ __constant__ int OFFS0[7] = {0, 24576, 30720, 32256, 32640, 32736, 32760};
__device__ __constant__ int OFFS1[9] = {0, 393216, 491520, 516096, 522240,
                                        523776, 524160, 524256, 524280};
static const int H_OFFS0[7] = {0, 24576, 30720, 32256, 32640, 32736, 32760};
static const int H_OFFS1[9] = {0, 393216, 491520, 516096, 522240,
                               523776, 524160, 524256, 524280};

// footprint-slot offsets (64B units within fp region), index = level-3
__device__ __constant__ int FPO1C[7] = {0, 25350, 31884, 33618, 34104, 34254, 34308};
__device__ __constant__ int FPO0C[5] = {34332, 36066, 36552, 36702, 36756};

// fpify segment tables (contiguous scan order: dst slot index == global tid)
__device__ __constant__ int C_SEG_START[13] = {0, 25350, 31884, 33618, 34104, 34254,
                                               34308, 34332, 36066, 36552, 36702,
                                               36756, 36780};
__device__ __constant__ int C_SEG_R[12] = {64, 32, 16, 8, 4, 2, 1, 16, 8, 4, 2, 1};
__device__ __constant__ int C_SEG_SRC[12] = {491520, 516096, 522240, 523776, 524160,
                                             524256, 524280, 555006, 556542, 556926,
                                             557022, 557046};

struct PyrArgs {
    const void* src;    // source level: RGB float3 (rgba=0) or float4 (rgba=1)
    float4* dst[5];     // up to 5 successive output levels (RGBA)
    int R;              // source resolution
    int tpf;            // tiles per face edge
    int T;              // tile size
    int nlev;           // levels to produce
    int rgba;           // src layout flag
};

// Each workgroup: load one TxT source tile to LDS (as float4), emit nlev
// successive 2x2-mean levels (matches reference's recursive pairwise mean).
__global__ __launch_bounds__(256) void pyr_kernel(PyrArgs a0, PyrArgs a1, int split) {
    __shared__ float4 A[32 * 32];
    __shared__ float4 Bb[16 * 16];

    PyrArgs a = (blockIdx.x < (unsigned)split) ? a0 : a1;
    int bid = (blockIdx.x < (unsigned)split) ? blockIdx.x : blockIdx.x - split;

    const int tpf = a.tpf;
    const int face = bid / (tpf * tpf);
    const int tif = bid - face * tpf * tpf;
    const int ty = tif / tpf, tx = tif - (tif / tpf) * tpf;
    const int T = a.T, R = a.R;
    const int tid = threadIdx.x;
    const int baseY = ty * T, baseX = tx * T;

    const int total = T * T;
    if (a.rgba) {
        const float4* src = (const float4*)a.src;
        for (int idx = tid; idx < total; idx += 256) {
            int r = idx / T, c = idx - (idx / T) * T;
            A[r * T + c] = src[(size_t)(face * R + baseY + r) * R + baseX + c];
        }
    } else {
        const float* src = (const float*)a.src;
        for (int idx = tid; idx < total; idx += 256) {
            int r = idx / T, c = idx - (idx / T) * T;
            const float* p = src + ((size_t)(face * R + baseY + r) * R + baseX + c) * 3;
            A[r * T + c] = make_float4(p[0], p[1], p[2], 0.f);
        }
    }
    __syncthreads();

    float4* cur = A;
    float4* nxt = Bb;
    int curT = T;
    for (int l = 0; l < a.nlev; ++l) {
        const int nT = curT >> 1;
        const int Rg = R >> (l + 1);
        const int tb = T >> (l + 1);
        float4* dst = a.dst[l];
        const int n = nT * nT;
        for (int idx = tid; idx < n; idx += 256) {
            int ly = idx / nT, lx = idx - (idx / nT) * nT;
            float4 q00 = cur[(2 * ly) * curT + 2 * lx];
            float4 q01 = cur[(2 * ly) * curT + 2 * lx + 1];
            float4 q10 = cur[(2 * ly + 1) * curT + 2 * lx];
            float4 q11 = cur[(2 * ly + 1) * curT + 2 * lx + 1];
            float4 s = make_float4(0.25f * (q00.x + q01.x + q10.x + q11.x),
                                   0.25f * (q00.y + q01.y + q10.y + q11.y),
                                   0.25f * (q00.z + q01.z + q10.z + q11.z), 0.f);
            nxt[ly * nT + lx] = s;
            dst[(size_t)(face * Rg + ty * tb + ly) * Rg + tx * tb + lx] = s;
        }
        __syncthreads();
        float4* tmp = cur; cur = nxt; nxt = tmp;
        curT = nT;
    }
}

// Convert plain RGBA levels (>=3) into gather-ready footprints.
// One thread per footprint slot; slot index == global tid (contiguous layout).
__global__ __launch_bounds__(256) void fpify_kernel(const float4* __restrict__ ws4,
                                                    float4* __restrict__ fp4) {
    int t = blockIdx.x * 256 + threadIdx.x;
    if (t >= NFP) return;
    int s = 0;
#pragma unroll
    for (int k = 1; k <= 12; ++k)
        if (t >= C_SEG_START[k]) s = k;
    int local = t - C_SEG_START[s];
    int R = C_SEG_R[s];
    int per1 = R + 1;
    int per = per1 * per1;
    int face = local / per;
    int rem = local - face * per;
    int j = rem / per1;
    int i = rem - j * per1;
    const float4* fb = ws4 + C_SEG_SRC[s] + (size_t)face * R * R;
    // exact clamped 2x2 footprint for xi = i-1, yi = j-1
    int x0 = max(i - 1, 0), x1 = min(i, R - 1);
    int y0 = max(j - 1, 0), y1 = min(j, R - 1);
    float4 q00 = fb[y0 * R + x0];
    float4 q01 = fb[y0 * R + x1];
    float4 q10 = fb[y1 * R + x0];
    float4 q11 = fb[y1 * R + x1];
    size_t d = (size_t)t * 4;
    fp4[d]     = make_float4(q00.x, q00.y, q00.z, q01.x);
    fp4[d + 1] = make_float4(q01.y, q01.z, q10.x, q10.y);
    fp4[d + 2] = make_float4(q10.z, q11.x, q11.y, q11.z);
    // slot word 3 is pad, never read
}

// footprint bilinear tap: 3 contiguous dwordx4 from one 64B block
__device__ __forceinline__ void sample_level_fp(const float4* __restrict__ fp, int R,
                                                int face, float u, float v, float o[3]) {
    float xf = u * (float)R - 0.5f;
    float yf = v * (float)R - 0.5f;
    float x0f = floorf(xf), y0f = floorf(yf);
    float fx = xf - x0f, fy = yf - y0f;
    int i = min(max((int)x0f + 1, 0), R);
    int j = min(max((int)y0f + 1, 0), R);
    int per1 = R + 1;
    size_t base = (size_t)((face * per1 + j) * per1 + i) * 4;
    float4 A  = fp[base];
    float4 Bq = fp[base + 1];
    float4 C  = fp[base + 2];
    float w00 = (1.f - fx) * (1.f - fy);
    float w01 = fx * (1.f - fy);
    float w10 = (1.f - fx) * fy;
    float w11 = fx * fy;
    o[0] = w00 * A.x + w01 * A.w + w10 * Bq.z + w11 * C.y;
    o[1] = w00 * A.y + w01 * Bq.x + w10 * Bq.w + w11 * C.z;
    o[2] = w00 * A.z + w01 * Bq.y + w10 * C.x + w11 * C.w;
}

// bilinear tap from RGBA plain level (levels 1..2 — rare)
__device__ __forceinline__ void bilin4(const float4* __restrict__ tex, int R,
                                       int face, float u, float v, float o[3]) {
    float xf = u * (float)R - 0.5f;
    float yf = v * (float)R - 0.5f;
    float x0f = floorf(xf), y0f = floorf(yf);
    float fx = xf - x0f, fy = yf - y0f;
    int xi = (int)x0f, yi = (int)y0f;
    int x0 = min(max(xi, 0), R - 1);
    int x1 = min(max(xi + 1, 0), R - 1);
    int y0 = min(max(yi, 0), R - 1);
    int y1 = min(max(yi + 1, 0), R - 1);
    const float4* base = tex + (size_t)face * R * R;
    float4 p00 = base[y0 * R + x0];
    float4 p01 = base[y0 * R + x1];
    float4 p10 = base[y1 * R + x0];
    float4 p11 = base[y1 * R + x1];
    float w00 = (1.f - fx) * (1.f - fy);
    float w01 = fx * (1.f - fy);
    float w10 = (1.f - fx) * fy;
    float w11 = fx * fy;
    o[0] = w00 * p00.x + w01 * p01.x + w10 * p10.x + w11 * p11.x;
    o[1] = w00 * p00.y + w01 * p01.y + w10 * p10.y + w11 * p11.y;
    o[2] = w00 * p00.z + w01 * p01.z + w10 * p10.z + w11 * p11.z;
}

// bilinear tap from the RGB base texture (level 0 — essentially never)
__device__ __forceinline__ void bilin3(const float* __restrict__ tex, int R,
                                       int face, float u, float v, float o[3]) {
    float xf = u * (float)R - 0.5f;
    float yf = v * (float)R - 0.5f;
    float x0f = floorf(xf), y0f = floorf(yf);
    float fx = xf - x0f, fy = yf - y0f;
    int xi = (int)x0f, yi = (int)y0f;
    int x0 = min(max(xi, 0), R - 1);
    int x1 = min(max(xi + 1, 0), R - 1);
    int y0 = min(max(yi, 0), R - 1);
    int y1 = min(max(yi + 1, 0), R - 1);
    const float* base = tex + (size_t)face * R * R * 3;
    const float* p00 = base + (y0 * R + x0) * 3;
    const float* p01 = base + (y0 * R + x1) * 3;
    const float* p10 = base + (y1 * R + x0) * 3;
    const float* p11 = base + (y1 * R + x1) * 3;
    float w00 = (1.f - fx) * (1.f - fy);
    float w01 = fx * (1.f - fy);
    float w10 = (1.f - fx) * fy;
    float w11 = fx * fy;
#pragma unroll
    for (int c = 0; c < 3; ++c)
        o[c] = w00 * p00[c] + w01 * p01[c] + w10 * p10[c] + w11 * p11[c];
}

__device__ __forceinline__ void sample_pyr(const float* __restrict__ base_tex,
                                           const float4* __restrict__ pyr,
                                           const int* offs,
                                           const float4* __restrict__ fp4,
                                           const int* fpoffs,
                                           int lmax, int R0,
                                           int face, float u, float v, float mip,
                                           float o[3]) {
    float m = fminf(fmaxf(mip, 0.f), (float)lmax);
    float l0f = floorf(m);
    int l0 = (int)l0f;
    float f = m - l0f;
    float c0[3];
    if (l0 >= 3)
        sample_level_fp(fp4 + (size_t)fpoffs[l0 - 3] * 4, R0 >> l0, face, u, v, c0);
    else if (l0 == 0)
        bilin3(base_tex, R0, face, u, v, c0);
    else
        bilin4(pyr + offs[l0 - 1], R0 >> l0, face, u, v, c0);
    if (f > 0.f && l0 < lmax) {
        float c1[3];
        int l1 = l0 + 1;
        if (l1 >= 3)
            sample_level_fp(fp4 + (size_t)fpoffs[l1 - 3] * 4, R0 >> l1, face, u, v, c1);
        else
            bilin4(pyr + offs[l1 - 1], R0 >> l1, face, u, v, c1);
        float w0 = 1.f - f;
#pragma unroll
        for (int c = 0; c < 3; ++c) o[c] = w0 * c0[c] + f * c1[c];
    } else {
#pragma unroll
        for (int c = 0; c < 3; ++c) o[c] = c0[c];
    }
}

__global__ __launch_bounds__(256) void sample_kernel(
    const float* __restrict__ vd, const float* __restrict__ sa,
    const float* __restrict__ nu, const float* __restrict__ tex0,
    const float* __restrict__ tex1, const float* __restrict__ sb,
    const float* __restrict__ sm, const float* __restrict__ smb,
    const float4* __restrict__ pyr0, const float4* __restrict__ pyr1,
    const float4* __restrict__ fp4, float* __restrict__ out, int n) {
    int i = blockIdx.x * 256 + threadIdx.x;
    if (i >= n) return;

    float x = vd[3 * i + 0];
    float y = vd[3 * i + 1];
    float z = vd[3 * i + 2];
    float ax = fabsf(x), ay = fabsf(y), az = fabsf(z);

    bool is_x = (ax >= ay) && (ax >= az);
    bool is_y = (!is_x) && (ay >= az);

    int face;
    float ma, sc, tc;
    if (is_x) {
        face = (x >= 0.f) ? 0 : 1;
        ma = ax;
        sc = (x >= 0.f) ? -z : z;
        tc = -y;
    } else if (is_y) {
        face = (y >= 0.f) ? 2 : 3;
        ma = ay;
        sc = x;
        tc = (y >= 0.f) ? z : -z;
    } else {
        face = (z >= 0.f) ? 4 : 5;
        ma = az;
        sc = (z >= 0.f) ? x : -x;
        tc = -y;
    }
    float u = 0.5f * (sc / ma + 1.f);
    float t = 0.5f * (tc / ma + 1.f);

    // miplevel
    float distortion = 1.f / ma;
    float saTexel = distortion / 512.f / 512.f;
    float mip = (sa[i] - logf(saTexel)) / 1.3862943611198906f / 2.0f +
                smb[0] + 0.5f * nu[i];
    mip = fmaxf(mip, 0.f);

    float s0[3], s1[3];
    sample_pyr(tex0, pyr0, OFFS0, fp4, FPO0C, 7, 128, face, u, t, mip, s0);
    sample_pyr(tex1, pyr1, OFFS1, fp4, FPO1C, 9, 512, face, u, t, mip, s1);

    float b = fminf(fmaxf(sb[0], -1.f), 2.f);
    float mul = sm[0];
#pragma unroll
    for (int c = 0; c < 3; ++c) {
        float e = expf(b + mul * (s0[c] + s1[c]));
        out[3 * i + c] = fminf(fmaxf(e, 0.01f), 1000.f);
    }
}

extern "C" void kernel_launch(void* const* d_in, const int* in_sizes, int n_in,
                              void* d_out, int out_size, void* d_ws, size_t ws_size,
                              hipStream_t stream) {
    const float* vd = (const float*)d_in[0];
    const float* sa = (const float*)d_in[1];
    const float* nu = (const float*)d_in[2];
    const float* tex0 = (const float*)d_in[3];  // (6,128,128,3)
    const float* tex1 = (const float*)d_in[4];  // (6,512,512,3)
    const float* br = (const float*)d_in[5];
    const float* mu = (const float*)d_in[6];
    const float* mb = (const float*)d_in[7];
    float* out = (float*)d_out;

    float4* pyr1 = (float4*)d_ws;
    float4* pyr0 = pyr1 + NPYR1_4;
    float4* fp4 = pyr1 + FPB;

    const int B = in_sizes[1];

    // --- pyramid build, launch 1: big levels (1..5 of each) ---
    PyrArgs a0{}, a1{};
    a0.src = tex1; a0.R = 512; a0.tpf = 16; a0.T = 32; a0.nlev = 5; a0.rgba = 0;
    for (int l = 0; l < 5; ++l) a0.dst[l] = pyr1 + H_OFFS1[l];
    a1.src = tex0; a1.R = 128; a1.tpf = 4; a1.T = 32; a1.nlev = 5; a1.rgba = 0;
    for (int l = 0; l < 5; ++l) a1.dst[l] = pyr0 + H_OFFS0[l];
    int split1 = 6 * 16 * 16;
    int grid1 = split1 + 6 * 4 * 4;
    hipLaunchKernelGGL(pyr_kernel, dim3(grid1), dim3(256), 0, stream, a0, a1, split1);

    // --- pyramid build, launch 2: tails ---
    PyrArgs b0{}, b1{};
    b0.src = pyr1 + H_OFFS1[4]; b0.R = 16; b0.tpf = 1; b0.T = 16; b0.nlev = 4; b0.rgba = 1;
    for (int l = 0; l < 4; ++l) b0.dst[l] = pyr1 + H_OFFS1[5 + l];
    b1.src = pyr0 + H_OFFS0[4]; b1.R = 4; b1.tpf = 1; b1.T = 4; b1.nlev = 2; b1.rgba = 1;
    for (int l = 0; l < 2; ++l) b1.dst[l] = pyr0 + H_OFFS0[5 + l];
    hipLaunchKernelGGL(pyr_kernel, dim3(12), dim3(256), 0, stream, b0, b1, 6);

    // --- footprint conversion for levels >= 3 ---
    hipLaunchKernelGGL(fpify_kernel, dim3((NFP + 255) / 256), dim3(256), 0, stream,
                       (const float4*)d_ws, fp4);

    // --- sampling ---
    int grid = (B + 255) / 256;
    hipLaunchKernelGGL(sample_kernel, dim3(grid), dim3(256), 0, stream,
                       vd, sa, nu, tex0, tex1, br, mu, mb, pyr0, pyr1, fp4, out, B);
}

// Round 2
// 119.425 us; speedup vs baseline: 1.1830x; 1.1830x over previous
//
#include <hip/hip_runtime.h>
#include <math.h>

// ---------------------------------------------------------------------------
// HierarchicalCubeMap, round 4:
//  - 3 launches (pyramid big-levels, tails+footprints, sample)
//  - footprints emitted from LDS in the tail kernel (fpify kernel removed)
//  - pyr launch1 uses vectorized dwordx4 tile loads (raw float LDS stage)
//  - sample kernel: wave-uniform fast path for l0 in [3,7) (covers ~100% of
//    rays), register-selected fp offsets, __logf/__expf/__frcp_rn
//
// ws layout (float4 units):
//   pyr1 plain (512 base, levels 1..5 used): [0 .. 524286)
//   pyr0 plain (128 base, levels 1..5 used): [524286 .. 557052)
//   footprints (levels >=3, both pyrs):      [557052 .. 557052 + 36780*4)
// ---------------------------------------------------------------------------

#define NPYR1_4 524286
#define FPB 557052   // float4 offset of footprint region (64B aligned)
#define NFP 36780    // total footprint slots
#define NSTANDALONE 35988  // fp slots produced by standalone blocks (levels 3-5)

// plain-level offsets in float4 units, index = level-1
__device__ __constant__ int OFFS0[7] = {0, 24576, 30720, 32256, 32640, 32736, 32760};
__device__ __constant__ int OFFS1[9] = {0, 393216, 491520, 516096, 522240,
                                        523776, 524160, 524256, 524280};
static const int H_OFFS0[5] = {0, 24576, 30720, 32256, 32640};
static const int H_OFFS1[5] = {0, 393216, 491520, 516096, 522240};

// footprint-slot offsets (64B units within fp region), index = level-3
__device__ __constant__ int FPO1C[7] = {0, 25350, 31884, 33618, 34104, 34254, 34308};
__device__ __constant__ int FPO0C[5] = {34332, 36066, 36552, 36702, 36756};

// tail-emitted fp bases: pyr1 levels 6..9, pyr0 levels 6..7
__device__ __constant__ int FPB1T[4] = {33618, 34104, 34254, 34308};
__device__ __constant__ int FPB0T[2] = {36702, 36756};

// standalone fp segments (levels 3-5 of both pyramids, built by launch 1)
__device__ __constant__ int S_START[7] = {0, 25350, 31884, 33618, 35352, 35838, 35988};
__device__ __constant__ int S_R[6]     = {64, 32, 16, 16, 8, 4};
__device__ __constant__ int S_SRC[6]   = {491520, 516096, 522240, 555006, 556542, 556926};
__device__ __constant__ int S_DST[6]   = {0, 25350, 31884, 34332, 36066, 36552};

struct PyrArgs {
    const float* src;   // RGB float3 base texture
    float4* dst[5];     // levels 1..5 (RGBA)
    int R;              // source resolution (512 or 128)
    int tpf;            // tiles per face edge (16 or 4)
};

// Launch 1: each block reduces one 32x32 source tile -> levels 1..5.
// Source loaded as 24 aligned dwordx4 per row (tile row = 384B, 16B-aligned).
__global__ __launch_bounds__(256) void pyr_kernel(PyrArgs a0, PyrArgs a1, int split) {
    __shared__ float raw[32 * 96];   // 32 rows x 32 texels x 3 ch
    __shared__ float4 A[16 * 16];
    __shared__ float4 Bb[8 * 8];

    PyrArgs a = (blockIdx.x < (unsigned)split) ? a0 : a1;
    int bid = (blockIdx.x < (unsigned)split) ? blockIdx.x : blockIdx.x - split;

    const int tpf = a.tpf, R = a.R;
    const int face = bid / (tpf * tpf);
    const int tif = bid - face * tpf * tpf;
    const int ty = tif / tpf, tx = tif - (tif / tpf) * tpf;
    const int tid = threadIdx.x;
    const int baseY = ty * 32, baseX = tx * 32;

    // vectorized tile load: 768 float4
    const float4* src4 = (const float4*)a.src;
    float4* raw4 = (float4*)raw;
    for (int idx = tid; idx < 768; idx += 256) {
        int r = idx / 24, c = idx - (idx / 24) * 24;
        size_t fidx = ((size_t)(face * R + baseY + r) * R + baseX) * 3;  // %4==0
        raw4[r * 24 + c] = src4[fidx / 4 + c];
    }
    __syncthreads();

    // stage 1: 32x32 raw RGB -> 16x16 RGBA (level 1)
    {
        int Rg = R >> 1;
        float4* dst = a.dst[0];
        int ly = tid >> 4, lx = tid & 15;
        const float* r0 = raw + (2 * ly) * 96 + 6 * lx;
        const float* r1 = r0 + 96;
        float4 s = make_float4(0.25f * (r0[0] + r0[3] + r1[0] + r1[3]),
                               0.25f * (r0[1] + r0[4] + r1[1] + r1[4]),
                               0.25f * (r0[2] + r0[5] + r1[2] + r1[5]), 0.f);
        A[tid] = s;
        dst[(size_t)(face * Rg + ty * 16 + ly) * Rg + tx * 16 + lx] = s;
    }
    __syncthreads();

    // stages 2..5
    float4* cur = A;
    float4* nxt = Bb;
    int curT = 16;
    for (int l = 1; l < 5; ++l) {
        const int nT = curT >> 1;
        const int Rg = R >> (l + 1);
        const int tb = 32 >> (l + 1);
        float4* dst = a.dst[l];
        const int n = nT * nT;
        for (int idx = tid; idx < n; idx += 256) {
            int ly = idx / nT, lx = idx - (idx / nT) * nT;
            float4 q00 = cur[(2 * ly) * curT + 2 * lx];
            float4 q01 = cur[(2 * ly) * curT + 2 * lx + 1];
            float4 q10 = cur[(2 * ly + 1) * curT + 2 * lx];
            float4 q11 = cur[(2 * ly + 1) * curT + 2 * lx + 1];
            float4 s = make_float4(0.25f * (q00.x + q01.x + q10.x + q11.x),
                                   0.25f * (q00.y + q01.y + q10.y + q11.y),
                                   0.25f * (q00.z + q01.z + q10.z + q11.z), 0.f);
            nxt[ly * nT + lx] = s;
            dst[(size_t)(face * Rg + ty * tb + ly) * Rg + tx * tb + lx] = s;
        }
        __syncthreads();
        float4* tmp = cur; cur = nxt; nxt = tmp;
        curT = nT;
    }
}

// Launch 2: blocks 0-11 = tails (pyr1 levels 6-9, pyr0 levels 6-7) emitting
// their footprints straight from LDS; blocks >=12 = standalone footprint
// conversion for launch-1 levels (3-5 of both pyramids).
__global__ __launch_bounds__(256) void tail_fp_kernel(const float4* __restrict__ ws4,
                                                      float4* __restrict__ fp4) {
    __shared__ float4 A[16 * 16];
    __shared__ float4 Bb[8 * 8];
    const int tid = threadIdx.x;
    const int b = blockIdx.x;

    if (b < 12) {
        const int isP0 = (b >= 6) ? 1 : 0;
        const int face = isP0 ? (b - 6) : b;
        const int R0 = isP0 ? 4 : 16;
        const int nlev = isP0 ? 2 : 4;
        const int srcoff = isP0 ? (NPYR1_4 + 32640) : 522240;  // level-5 plains
        const float4* src = ws4 + srcoff + (size_t)face * R0 * R0;
        for (int idx = tid; idx < R0 * R0; idx += 256) A[idx] = src[idx];
        __syncthreads();

        float4* cur = A;
        float4* nxt = Bb;
        int curT = R0;
        for (int l = 0; l < nlev; ++l) {
            const int nT = curT >> 1;
            for (int idx = tid; idx < nT * nT; idx += 256) {
                int ly = idx / nT, lx = idx - (idx / nT) * nT;
                float4 q00 = cur[(2 * ly) * curT + 2 * lx];
                float4 q01 = cur[(2 * ly) * curT + 2 * lx + 1];
                float4 q10 = cur[(2 * ly + 1) * curT + 2 * lx];
                float4 q11 = cur[(2 * ly + 1) * curT + 2 * lx + 1];
                nxt[ly * nT + lx] =
                    make_float4(0.25f * (q00.x + q01.x + q10.x + q11.x),
                                0.25f * (q00.y + q01.y + q10.y + q11.y),
                                0.25f * (q00.z + q01.z + q10.z + q11.z), 0.f);
            }
            __syncthreads();
            // emit footprints for this level from LDS
            const int Rl = nT, per1 = Rl + 1;
            const int fpbase = (isP0 ? FPB0T[l] : FPB1T[l]) + face * per1 * per1;
            for (int idx = tid; idx < per1 * per1; idx += 256) {
                int j = idx / per1, i = idx - (idx / per1) * per1;
                int x0 = max(i - 1, 0), x1 = min(i, Rl - 1);
                int y0 = max(j - 1, 0), y1 = min(j, Rl - 1);
                float4 q00 = nxt[y0 * Rl + x0];
                float4 q01 = nxt[y0 * Rl + x1];
                float4 q10 = nxt[y1 * Rl + x0];
                float4 q11 = nxt[y1 * Rl + x1];
                size_t d = (size_t)(fpbase + idx) * 4;
                fp4[d]     = make_float4(q00.x, q00.y, q00.z, q01.x);
                fp4[d + 1] = make_float4(q01.y, q01.z, q10.x, q10.y);
                fp4[d + 2] = make_float4(q10.z, q11.x, q11.y, q11.z);
            }
            __syncthreads();
            float4* tmp = cur; cur = nxt; nxt = tmp;
            curT = nT;
        }
    } else {
        int t = (b - 12) * 256 + tid;
        if (t >= NSTANDALONE) return;
        int s = 0;
#pragma unroll
        for (int k = 1; k <= 5; ++k)
            if (t >= S_START[k]) s = k;
        int local = t - S_START[s];
        int R = S_R[s];
        int per1 = R + 1;
        int per = per1 * per1;
        int face = local / per;
        int rem = local - face * per;
        int j = rem / per1;
        int i = rem - j * per1;
        const float4* fb = ws4 + S_SRC[s] + (size_t)face * R * R;
        int x0 = max(i - 1, 0), x1 = min(i, R - 1);
        int y0 = max(j - 1, 0), y1 = min(j, R - 1);
        float4 q00 = fb[y0 * R + x0];
        float4 q01 = fb[y0 * R + x1];
        float4 q10 = fb[y1 * R + x0];
        float4 q11 = fb[y1 * R + x1];
        size_t d = (size_t)(S_DST[s] + local) * 4;
        fp4[d]     = make_float4(q00.x, q00.y, q00.z, q01.x);
        fp4[d + 1] = make_float4(q01.y, q01.z, q10.x, q10.y);
        fp4[d + 2] = make_float4(q10.z, q11.x, q11.y, q11.z);
    }
}

// footprint bilinear tap: 3 contiguous dwordx4 from one 64B block
__device__ __forceinline__ void sample_level_fp(const float4* __restrict__ fp, int R,
                                                int face, float u, float v, float o[3]) {
    float xf = u * (float)R - 0.5f;
    float yf = v * (float)R - 0.5f;
    float x0f = floorf(xf), y0f = floorf(yf);
    float fx = xf - x0f, fy = yf - y0f;
    int i = min(max((int)x0f + 1, 0), R);
    int j = min(max((int)y0f + 1, 0), R);
    int per1 = R + 1;
    size_t base = (size_t)((face * per1 + j) * per1 + i) * 4;
    float4 A  = fp[base];
    float4 Bq = fp[base + 1];
    float4 C  = fp[base + 2];
    float w00 = (1.f - fx) * (1.f - fy);
    float w01 = fx * (1.f - fy);
    float w10 = (1.f - fx) * fy;
    float w11 = fx * fy;
    o[0] = w00 * A.x + w01 * A.w + w10 * Bq.z + w11 * C.y;
    o[1] = w00 * A.y + w01 * Bq.x + w10 * Bq.w + w11 * C.z;
    o[2] = w00 * A.z + w01 * Bq.y + w10 * C.x + w11 * C.w;
}

// bilinear tap from RGBA plain level (levels 1..2 — rare slow path)
__device__ __forceinline__ void bilin4(const float4* __restrict__ tex, int R,
                                       int face, float u, float v, float o[3]) {
    float xf = u * (float)R - 0.5f;
    float yf = v * (float)R - 0.5f;
    float x0f = floorf(xf), y0f = floorf(yf);
    float fx = xf - x0f, fy = yf - y0f;
    int xi = (int)x0f, yi = (int)y0f;
    int x0 = min(max(xi, 0), R - 1);
    int x1 = min(max(xi + 1, 0), R - 1);
    int y0 = min(max(yi, 0), R - 1);
    int y1 = min(max(yi + 1, 0), R - 1);
    const float4* base = tex + (size_t)face * R * R;
    float4 p00 = base[y0 * R + x0];
    float4 p01 = base[y0 * R + x1];
    float4 p10 = base[y1 * R + x0];
    float4 p11 = base[y1 * R + x1];
    float w00 = (1.f - fx) * (1.f - fy);
    float w01 = fx * (1.f - fy);
    float w10 = (1.f - fx) * fy;
    float w11 = fx * fy;
    o[0] = w00 * p00.x + w01 * p01.x + w10 * p10.x + w11 * p11.x;
    o[1] = w00 * p00.y + w01 * p01.y + w10 * p10.y + w11 * p11.y;
    o[2] = w00 * p00.z + w01 * p01.z + w10 * p10.z + w11 * p11.z;
}

// bilinear tap from the RGB base texture (level 0 — essentially never)
__device__ __forceinline__ void bilin3(const float* __restrict__ tex, int R,
                                       int face, float u, float v, float o[3]) {
    float xf = u * (float)R - 0.5f;
    float yf = v * (float)R - 0.5f;
    float x0f = floorf(xf), y0f = floorf(yf);
    float fx = xf - x0f, fy = yf - y0f;
    int xi = (int)x0f, yi = (int)y0f;
    int x0 = min(max(xi, 0), R - 1);
    int x1 = min(max(xi + 1, 0), R - 1);
    int y0 = min(max(yi, 0), R - 1);
    int y1 = min(max(yi + 1, 0), R - 1);
    const float* base = tex + (size_t)face * R * R * 3;
    const float* p00 = base + (y0 * R + x0) * 3;
    const float* p01 = base + (y0 * R + x1) * 3;
    const float* p10 = base + (y1 * R + x0) * 3;
    const float* p11 = base + (y1 * R + x1) * 3;
    float w00 = (1.f - fx) * (1.f - fy);
    float w01 = fx * (1.f - fy);
    float w10 = (1.f - fx) * fy;
    float w11 = fx * fy;
#pragma unroll
    for (int c = 0; c < 3; ++c)
        o[c] = w00 * p00[c] + w01 * p01[c] + w10 * p10[c] + w11 * p11[c];
}

// generic (slow-path) sampler — handles all clamp/level cases
__device__ __forceinline__ void sample_pyr(const float* __restrict__ base_tex,
                                           const float4* __restrict__ pyr,
                                           const int* offs,
                                           const float4* __restrict__ fp4,
                                           const int* fpoffs,
                                           int lmax, int R0,
                                           int face, float u, float v, float mip,
                                           float o[3]) {
    float m = fminf(fmaxf(mip, 0.f), (float)lmax);
    float l0f = floorf(m);
    int l0 = (int)l0f;
    float f = m - l0f;
    float c0[3];
    if (l0 >= 3)
        sample_level_fp(fp4 + (size_t)fpoffs[l0 - 3] * 4, R0 >> l0, face, u, v, c0);
    else if (l0 == 0)
        bilin3(base_tex, R0, face, u, v, c0);
    else
        bilin4(pyr + offs[l0 - 1], R0 >> l0, face, u, v, c0);
    if (f > 0.f && l0 < lmax) {
        float c1[3];
        int l1 = l0 + 1;
        if (l1 >= 3)
            sample_level_fp(fp4 + (size_t)fpoffs[l1 - 3] * 4, R0 >> l1, face, u, v, c1);
        else
            bilin4(pyr + offs[l1 - 1], R0 >> l1, face, u, v, c1);
        float w0 = 1.f - f;
#pragma unroll
        for (int c = 0; c < 3; ++c) o[c] = w0 * c0[c] + f * c1[c];
    } else {
#pragma unroll
        for (int c = 0; c < 3; ++c) o[c] = c0[c];
    }
}

__global__ __launch_bounds__(256) void sample_kernel(
    const float* __restrict__ vd, const float* __restrict__ sa,
    const float* __restrict__ nu, const float* __restrict__ tex0,
    const float* __restrict__ tex1, const float* __restrict__ sb,
    const float* __restrict__ sm, const float* __restrict__ smb,
    const float4* __restrict__ pyr0, const float4* __restrict__ pyr1,
    const float4* __restrict__ fp4, float* __restrict__ out, int n) {
    int i = blockIdx.x * 256 + threadIdx.x;
    if (i >= n) return;

    float x = vd[3 * i + 0];
    float y = vd[3 * i + 1];
    float z = vd[3 * i + 2];
    float ax = fabsf(x), ay = fabsf(y), az = fabsf(z);

    bool is_x = (ax >= ay) && (ax >= az);
    bool is_y = (!is_x) && (ay >= az);

    int face;
    float ma, sc, tc;
    if (is_x) {
        face = (x >= 0.f) ? 0 : 1;
        ma = ax;
        sc = (x >= 0.f) ? -z : z;
        tc = -y;
    } else if (is_y) {
        face = (y >= 0.f) ? 2 : 3;
        ma = ay;
        sc = x;
        tc = (y >= 0.f) ? z : -z;
    } else {
        face = (z >= 0.f) ? 4 : 5;
        ma = az;
        sc = (z >= 0.f) ? x : -x;
        tc = -y;
    }
    float rma = __frcp_rn(ma);
    float u = 0.5f * (sc * rma + 1.f);
    float t = 0.5f * (tc * rma + 1.f);

    // miplevel: (sa - log(saTexel))/log(4)/2 + mipbias + 0.5*nu,
    // -log(saTexel) = log(ma) + log(512*512)
    float mip = (sa[i] + 12.476649250079015f + __logf(ma)) * 0.36067376022224085f +
                smb[0] + 0.5f * nu[i];
    mip = fmaxf(mip, 0.f);

    float l0f = floorf(mip);
    int l0 = (int)l0f;
    float f = mip - l0f;

    float s0[3], s1[3];
    bool fast = (l0 >= 3) && (l0 < 7);
    if (__all(fast)) {
        // register-selected fp offsets (no divergent table loads)
        int oA = (l0 == 3) ? 0     : (l0 == 4) ? 25350 : (l0 == 5) ? 31884 : 33618;
        int oB = (l0 == 3) ? 25350 : (l0 == 4) ? 31884 : (l0 == 5) ? 33618 : 34104;
        int oC = (l0 == 3) ? 34332 : (l0 == 4) ? 36066 : (l0 == 5) ? 36552 : 36702;
        int oD = (l0 == 3) ? 36066 : (l0 == 4) ? 36552 : (l0 == 5) ? 36702 : 36756;
        float a0v[3], a1v[3], b0v[3], b1v[3];
        sample_level_fp(fp4 + (size_t)oA * 4, 512 >> l0, face, u, t, a0v);
        sample_level_fp(fp4 + (size_t)oB * 4, 512 >> (l0 + 1), face, u, t, a1v);
        sample_level_fp(fp4 + (size_t)oC * 4, 128 >> l0, face, u, t, b0v);
        sample_level_fp(fp4 + (size_t)oD * 4, 128 >> (l0 + 1), face, u, t, b1v);
        float w0 = 1.f - f;
#pragma unroll
        for (int c = 0; c < 3; ++c) {
            s0[c] = w0 * a1v[c] * 0.f + (w0 * a0v[c] + f * a1v[c]);  // keep order
            s0[c] = w0 * a0v[c] + f * a1v[c];
            s1[c] = w0 * b0v[c] + f * b1v[c];
        }
    } else {
        sample_pyr(tex0, pyr0, OFFS0, fp4, FPO0C, 7, 128, face, u, t, mip, s0);
        sample_pyr(tex1, pyr1, OFFS1, fp4, FPO1C, 9, 512, face, u, t, mip, s1);
    }

    float b = fminf(fmaxf(sb[0], -1.f), 2.f);
    float mul = sm[0];
#pragma unroll
    for (int c = 0; c < 3; ++c) {
        float e = __expf(b + mul * (s0[c] + s1[c]));
        out[3 * i + c] = fminf(fmaxf(e, 0.01f), 1000.f);
    }
}

extern "C" void kernel_launch(void* const* d_in, const int* in_sizes, int n_in,
                              void* d_out, int out_size, void* d_ws, size_t ws_size,
                              hipStream_t stream) {
    const float* vd = (const float*)d_in[0];
    const float* sa = (const float*)d_in[1];
    const float* nu = (const float*)d_in[2];
    const float* tex0 = (const float*)d_in[3];  // (6,128,128,3)
    const float* tex1 = (const float*)d_in[4];  // (6,512,512,3)
    const float* br = (const float*)d_in[5];
    const float* mu = (const float*)d_in[6];
    const float* mb = (const float*)d_in[7];
    float* out = (float*)d_out;

    float4* pyr1 = (float4*)d_ws;
    float4* pyr0 = pyr1 + NPYR1_4;
    float4* fp4 = pyr1 + FPB;

    const int B = in_sizes[1];

    // --- launch 1: levels 1..5 of both pyramids ---
    PyrArgs a0{}, a1{};
    a0.src = tex1; a0.R = 512; a0.tpf = 16;
    for (int l = 0; l < 5; ++l) a0.dst[l] = pyr1 + H_OFFS1[l];
    a1.src = tex0; a1.R = 128; a1.tpf = 4;
    for (int l = 0; l < 5; ++l) a1.dst[l] = pyr0 + H_OFFS0[l];
    int split1 = 6 * 16 * 16;
    int grid1 = split1 + 6 * 4 * 4;
    hipLaunchKernelGGL(pyr_kernel, dim3(grid1), dim3(256), 0, stream, a0, a1, split1);

    // --- launch 2: tails (levels 6+) with in-LDS footprints + standalone fp ---
    int grid2 = 12 + (NSTANDALONE + 255) / 256;
    hipLaunchKernelGGL(tail_fp_kernel, dim3(grid2), dim3(256), 0, stream,
                       (const float4*)d_ws, fp4);

    // --- launch 3: sampling ---
    int grid = (B + 255) / 256;
    hipLaunchKernelGGL(sample_kernel, dim3(grid), dim3(256), 0, stream,
                       vd, sa, nu, tex0, tex1, br, mu, mb, pyr0, pyr1, fp4, out, B);
}